// Round 11
// baseline (408.893 us; speedup 1.0000x reference)
//
#include <hip/hip_runtime.h>
#include <hip/hip_fp16.h>
#include <math.h>

#define NN 50000
#define EE 1600000
#define ETOT (EE + NN)
#define NEG_SLOPE 0.2f
#define BN_EPS 1e-5f
#define PAY_BLOCKS 1024
#define NPB 64                        // nodes per bucket
#define NBUCK ((NN + NPB - 1) / NPB)  // 782
#define CHUNK 8192                    // edges per bscat chunk
#define NCHUNK ((EE + CHUNK - 1) / CHUNK)

// pairs[i] (bucket-grouped, 8B): {x = (dst_local<<21) | eid, y = src}
// CSR-order split arrays: recAE1 (uint2), recAE2 (uint2), rec3 (f32), recSrc (i32)
// cbuild: quad-per-edge — 4 lanes split the 64B ea row, butterfly-reduce the 9 alpha dots.

static __device__ inline unsigned pkh2(float a, float b) {
  __half ha = __float2half_rn(a), hb = __float2half_rn(b);
  unsigned short ua = *(unsigned short*)&ha, ub = *(unsigned short*)&hb;
  return ((unsigned)ub << 16) | ua;
}
static __device__ inline float upkh(unsigned u, int hi) {
  unsigned short s = hi ? (unsigned short)(u >> 16) : (unsigned short)(u & 0xffff);
  __half h = *(__half*)&s;
  return __half2float(h);
}

// ---------------- M[d,h] = sum_c We[d, h*32+c] * ae[h,c] (per layer) ----------------
__global__ void compute_M_k(const float* __restrict__ We1, const float* __restrict__ ae1,
                            const float* __restrict__ We2, const float* __restrict__ ae2,
                            const float* __restrict__ We3, const float* __restrict__ ae3,
                            float* __restrict__ M) {
  int t = threadIdx.x;
  if (t < 64) {
    int d = t >> 2, h = t & 3;
    float s1 = 0.f, s2 = 0.f;
    for (int c = 0; c < 32; ++c) {
      s1 += We1[d * 128 + h * 32 + c] * ae1[h * 32 + c];
      s2 += We2[d * 128 + h * 32 + c] * ae2[h * 32 + c];
    }
    M[t] = s1;
    M[64 + t] = s2;
  }
  if (t < 16) {
    M[128 + t] = We3[t * 2] * ae3[0] + We3[t * 2 + 1] * ae3[1];
  }
}

// ---- bcount: fused dst bucket-histogram + ea mean partials (one ea stream) ----
__global__ __launch_bounds__(256) void bcount_k(const int* __restrict__ dst,
                                                const float* __restrict__ ea,
                                                int* __restrict__ bucketCnt,
                                                float* __restrict__ mean_part) {
  __shared__ int hist[1024];
  int t = threadIdx.x;
  for (int b = t; b < 1024; b += 256) hist[b] = 0;
  __syncthreads();
  float macc[16];
#pragma unroll
  for (int d = 0; d < 16; ++d) macc[d] = 0.f;
  for (int e = blockIdx.x * 256 + t; e < EE; e += PAY_BLOCKS * 256) {
    const float4* p = (const float4*)(ea + (size_t)e * 16);
    float4 q0 = p[0], q1 = p[1], q2 = p[2], q3 = p[3];
    macc[0] += q0.x; macc[1] += q0.y; macc[2] += q0.z; macc[3] += q0.w;
    macc[4] += q1.x; macc[5] += q1.y; macc[6] += q1.z; macc[7] += q1.w;
    macc[8] += q2.x; macc[9] += q2.y; macc[10] += q2.z; macc[11] += q2.w;
    macc[12] += q3.x; macc[13] += q3.y; macc[14] += q3.z; macc[15] += q3.w;
    atomicAdd(&hist[dst[e] >> 6], 1);
  }
#pragma unroll
  for (int d = 0; d < 16; ++d) {
#pragma unroll
    for (int off = 32; off; off >>= 1) macc[d] += __shfl_xor(macc[d], off, 64);
  }
  __shared__ float swsum[4][16];
  int w = t >> 6, l = t & 63;
  if (l == 0) {
#pragma unroll
    for (int d = 0; d < 16; ++d) swsum[w][d] = macc[d];
  }
  __syncthreads();
  if (t < 16) {
    mean_part[(size_t)blockIdx.x * 16 + t] =
        swsum[0][t] + swsum[1][t] + swsum[2][t] + swsum[3][t];
  }
  for (int b = t; b < NBUCK; b += 256)
    if (hist[b]) atomicAdd(&bucketCnt[b], hist[b]);
}

// -------- reduce mean partials -> asl[0..3]=L1, [4..7]=L2, [8]=L3 --------
__global__ __launch_bounds__(256) void selfloop_k(const float* __restrict__ mean_part,
                                                  const float* __restrict__ M,
                                                  float* __restrict__ alpha_sl) {
  __shared__ float s[256];
  int t = threadIdx.x;
  int d = t & 15, c = t >> 4;
  float v = 0.f;
  for (int i = c * 64; i < (c + 1) * 64; ++i) v += mean_part[(size_t)i * 16 + d];
  s[t] = v;
  __syncthreads();
  if (t < 16) {
    float sum = 0.f;
    for (int c2 = 0; c2 < 16; ++c2) sum += s[c2 * 16 + t];
    s[t] = sum / (float)EE;
  }
  __syncthreads();
  if (t < 9) {
    float r = 0.f;
    if (t < 4) {
      for (int dd = 0; dd < 16; ++dd) r += s[dd] * M[dd * 4 + t];
    } else if (t < 8) {
      int h = t - 4;
      for (int dd = 0; dd < 16; ++dd) r += s[dd] * M[64 + dd * 4 + h];
    } else {
      for (int dd = 0; dd < 16; ++dd) r += s[dd] * M[128 + dd];
    }
    alpha_sl[t] = r;
  }
}

// ---- scan NBUCK bucket totals -> pairs bases (pBase/bcur) and row bases (rBase) ----
__global__ __launch_bounds__(1024) void bscan_k(const int* __restrict__ bucketCnt,
                                                int* __restrict__ pBase,
                                                int* __restrict__ rBase,
                                                int* __restrict__ bcur) {
  __shared__ int s1[1024], s2[1024];
  int t = threadIdx.x;
  int cnt = (t < NBUCK) ? bucketCnt[t] : 0;
  int nn = 0;
  if (t < NBUCK) {
    int n0 = t * NPB;
    nn = NN - n0; if (nn > NPB) nn = NPB;
  }
  s1[t] = cnt;
  s2[t] = cnt + nn;
  __syncthreads();
  for (int off = 1; off < 1024; off <<= 1) {
    int a = (t >= off) ? s1[t - off] : 0;
    int b = (t >= off) ? s2[t - off] : 0;
    __syncthreads();
    s1[t] += a; s2[t] += b;
    __syncthreads();
  }
  if (t < NBUCK) {
    pBase[t] = s1[t] - cnt;
    rBase[t] = s2[t] - (cnt + nn);
    bcur[t] = s1[t] - cnt;
  }
  if (t == 0) { pBase[NBUCK] = EE; rBase[NBUCK] = ETOT; }
}

// ---- bucket scatter: per-chunk LDS histogram -> run reservation -> packed 8B writes ----
__global__ __launch_bounds__(256) void bscat_k(const int* __restrict__ dst,
                                               const int* __restrict__ src,
                                               int* __restrict__ bcur,
                                               uint2* __restrict__ pairs) {
  __shared__ int hist[1024];
  __shared__ int ofs[1024];
  int t = threadIdx.x;
  for (int c = blockIdx.x; c < NCHUNK; c += gridDim.x) {
    int cb = c * CHUNK;
    for (int b = t; b < 1024; b += 256) hist[b] = 0;
    __syncthreads();
#pragma unroll
    for (int k = 0; k < 8; ++k) {
      int e = cb + k * 1024 + t * 4;
      if (e < EE) {
        int4 d4 = *(const int4*)&dst[e];
        atomicAdd(&hist[d4.x >> 6], 1);
        atomicAdd(&hist[d4.y >> 6], 1);
        atomicAdd(&hist[d4.z >> 6], 1);
        atomicAdd(&hist[d4.w >> 6], 1);
      }
    }
    __syncthreads();
    for (int b = t; b < NBUCK; b += 256) {
      int h = hist[b];
      ofs[b] = h ? atomicAdd(&bcur[b], h) : 0;
      hist[b] = 0;
    }
    __syncthreads();
#pragma unroll
    for (int k = 0; k < 8; ++k) {
      int e = cb + k * 1024 + t * 4;
      if (e < EE) {
        int4 d4 = *(const int4*)&dst[e];
        int4 s4 = *(const int4*)&src[e];
        int dd[4] = {d4.x, d4.y, d4.z, d4.w};
        int sv[4] = {s4.x, s4.y, s4.z, s4.w};
#pragma unroll
        for (int j = 0; j < 4; ++j) {
          int b = dd[j] >> 6;
          int pos = ofs[b] + atomicAdd(&hist[b], 1);
          pairs[pos] = make_uint2(((unsigned)(dd[j] & (NPB - 1)) << 21) | (unsigned)(e + j),
                                  (unsigned)sv[j]);
        }
      }
    }
    __syncthreads();
  }
}

// ---- CSR build: one block/bucket; quad-per-edge ea gather + butterfly alpha dots ----
__global__ __launch_bounds__(256) void cbuild_k(const int* __restrict__ pBase,
                                                const int* __restrict__ rBase,
                                                const uint2* __restrict__ pairs,
                                                const float* __restrict__ ea,
                                                const float* __restrict__ M,
                                                const float* __restrict__ asl,
                                                uint2* __restrict__ recAE1,
                                                uint2* __restrict__ recAE2,
                                                float* __restrict__ rec3,
                                                int* __restrict__ recSrc,
                                                int* __restrict__ row_ofs) {
  __shared__ float sM[144];
  __shared__ int lcnt[NPB];
  __shared__ int ss[NPB];
  __shared__ int cur[NPB];
  int b = blockIdx.x;
  int t = threadIdx.x;
  if (t < 144) sM[t] = M[t];
  if (t < NPB) lcnt[t] = 0;
  __syncthreads();
  int n0 = b * NPB;
  int n1 = n0 + NPB; if (n1 > NN) n1 = NN;
  int nn = n1 - n0;
  int pb = pBase[b], pe = pBase[b + 1];
  for (int i = pb + t; i < pe; i += 256) atomicAdd(&lcnt[pairs[i].x >> 21], 1);
  __syncthreads();
  int v = (t < nn) ? (lcnt[t] + 1) : 0;
  if (t < NPB) ss[t] = v;
  __syncthreads();
  for (int off = 1; off < NPB; off <<= 1) {
    int a = (t >= off && t < NPB) ? ss[t - off] : 0;
    __syncthreads();
    if (t < NPB) ss[t] += a;
    __syncthreads();
  }
  int rb = rBase[b];
  if (t < nn) {
    int self = rb + ss[t] - v;  // exclusive prefix
    row_ofs[n0 + t] = self;
    cur[t] = self + 1;          // slot self reserved for the self loop
    recAE1[self] = make_uint2(pkh2(asl[0], asl[1]), pkh2(asl[2], asl[3]));
    recAE2[self] = make_uint2(pkh2(asl[4], asl[5]), pkh2(asl[6], asl[7]));
    rec3[self] = asl[8];
    recSrc[self] = n0 + t;
  }
  if (b == NBUCK - 1 && t == 0) row_ofs[NN] = ETOT;
  __syncthreads();

  // ---- edge phase: quad (4 lanes) per edge; lane l owns dims 4l..4l+3 ----
  int qid = t >> 2;   // 0..63
  int l = t & 3;
  int d0 = l * 4;
  for (int base2 = pb; base2 < pe; base2 += 256) {
    uint2 u[4];
    bool valid[4];
    float4 qv[4];
#pragma unroll
    for (int k = 0; k < 4; ++k) {
      int i = base2 + k * 64 + qid;
      valid[k] = (i < pe);
      if (valid[k]) u[k] = pairs[i];  // broadcast across the quad
    }
#pragma unroll
    for (int k = 0; k < 4; ++k) {
      if (valid[k])
        qv[k] = *(const float4*)(ea + (size_t)(u[k].x & 0x1FFFFF) * 16 + d0);
    }
#pragma unroll
    for (int k = 0; k < 4; ++k) {
      if (valid[k]) {
        float a1[4], a2[4];
#pragma unroll
        for (int h = 0; h < 4; ++h) {
          a1[h] = qv[k].x * sM[(d0 + 0) * 4 + h] + qv[k].y * sM[(d0 + 1) * 4 + h] +
                  qv[k].z * sM[(d0 + 2) * 4 + h] + qv[k].w * sM[(d0 + 3) * 4 + h];
          a2[h] = qv[k].x * sM[64 + (d0 + 0) * 4 + h] + qv[k].y * sM[64 + (d0 + 1) * 4 + h] +
                  qv[k].z * sM[64 + (d0 + 2) * 4 + h] + qv[k].w * sM[64 + (d0 + 3) * 4 + h];
        }
        float a3 = qv[k].x * sM[128 + d0] + qv[k].y * sM[128 + d0 + 1] +
                   qv[k].z * sM[128 + d0 + 2] + qv[k].w * sM[128 + d0 + 3];
        // butterfly over the quad: every lane ends with full 16-dim sums
#pragma unroll
        for (int off = 1; off <= 2; off <<= 1) {
#pragma unroll
          for (int h = 0; h < 4; ++h) {
            a1[h] += __shfl_xor(a1[h], off, 4);
            a2[h] += __shfl_xor(a2[h], off, 4);
          }
          a3 += __shfl_xor(a3, off, 4);
        }
        int pos = 0;
        if (l == 0) pos = atomicAdd(&cur[u[k].x >> 21], 1);
        pos = __shfl(pos, 0, 4);
        if (l == 0)      recAE1[pos] = make_uint2(pkh2(a1[0], a1[1]), pkh2(a1[2], a1[3]));
        else if (l == 1) recAE2[pos] = make_uint2(pkh2(a2[0], a2[1]), pkh2(a2[2], a2[3]));
        else if (l == 2) rec3[pos] = a3;
        else             recSrc[pos] = (int)u[k].y;
      }
    }
  }
}

// ---- GEMM 64x64 tiles + fused alpha epilogue; Y written as fp16 ----
__global__ __launch_bounds__(256) void gemm128a_k(const float* __restrict__ X,
                                                  const float* __restrict__ W,
                                                  const float* __restrict__ as,
                                                  const float* __restrict__ ad,
                                                  __half* __restrict__ Y,
                                                  float* __restrict__ asrc,
                                                  float* __restrict__ adst,
                                                  int nrows) {
  __shared__ float sW[128 * 64];
  __shared__ float sX[64 * 132];
  __shared__ float sas[128], sad[128];
  int t = threadIdx.x;
  int r0 = blockIdx.x * 64;
  int cb = blockIdx.y;  // column half: heads 2*cb, 2*cb+1
  if (t < 128) { sas[t] = as[t]; sad[t] = ad[t]; }
#pragma unroll
  for (int i = 0; i < 8; ++i) {
    int flat = t + i * 256;          // float4 index over 128x64 tile
    int k = flat >> 4, c4 = flat & 15;
    *(float4*)&sW[k * 64 + c4 * 4] = *(const float4*)&W[k * 128 + cb * 64 + c4 * 4];
  }
  int rows = nrows - r0; if (rows > 64) rows = 64;
#pragma unroll
  for (int i = 0; i < 8; ++i) {
    int flat = t + i * 256;          // float4 index over 64x128 tile
    int r = flat >> 5, k4 = flat & 31;
    if (r < rows)
      *(float4*)&sX[r * 132 + k4 * 4] = *(const float4*)&X[(size_t)(r0 + r) * 128 + k4 * 4];
  }
  __syncthreads();
  int cq = t & 15, rl = t >> 4;
  float4 acc[4];
#pragma unroll
  for (int i = 0; i < 4; ++i) acc[i] = make_float4(0.f, 0.f, 0.f, 0.f);

  for (int k = 0; k < 128; k += 4) {
    float4 w0 = *(float4*)&sW[(k + 0) * 64 + cq * 4];
    float4 w1 = *(float4*)&sW[(k + 1) * 64 + cq * 4];
    float4 w2 = *(float4*)&sW[(k + 2) * 64 + cq * 4];
    float4 w3 = *(float4*)&sW[(k + 3) * 64 + cq * 4];
#pragma unroll
    for (int i = 0; i < 4; ++i) {
      float4 xv = *(float4*)&sX[(rl + i * 16) * 132 + k];
      acc[i].x += xv.x * w0.x + xv.y * w1.x + xv.z * w2.x + xv.w * w3.x;
      acc[i].y += xv.x * w0.y + xv.y * w1.y + xv.z * w2.y + xv.w * w3.y;
      acc[i].z += xv.x * w0.z + xv.y * w1.z + xv.z * w2.z + xv.w * w3.z;
      acc[i].w += xv.x * w0.w + xv.y * w1.w + xv.z * w2.w + xv.w * w3.w;
    }
  }
  int h = cb * 2 + (cq >> 3);
  int col0 = cb * 64 + cq * 4;
#pragma unroll
  for (int i = 0; i < 4; ++i) {
    int r = rl + i * 16;
    if (r < rows) {
      uint2 st;
      st.x = pkh2(acc[i].x, acc[i].y);
      st.y = pkh2(acc[i].z, acc[i].w);
      *(uint2*)&Y[(size_t)(r0 + r) * 128 + col0] = st;
      float s1 = acc[i].x * sas[col0] + acc[i].y * sas[col0 + 1] +
                 acc[i].z * sas[col0 + 2] + acc[i].w * sas[col0 + 3];
      float s2 = acc[i].x * sad[col0] + acc[i].y * sad[col0 + 1] +
                 acc[i].z * sad[col0 + 2] + acc[i].w * sad[col0 + 3];
      s1 += __shfl_xor(s1, 1, 8); s1 += __shfl_xor(s1, 2, 8); s1 += __shfl_xor(s1, 4, 8);
      s2 += __shfl_xor(s2, 1, 8); s2 += __shfl_xor(s2, 2, 8); s2 += __shfl_xor(s2, 4, 8);
      if ((cq & 7) == 0) {
        asrc[(size_t)(r0 + r) * 4 + h] = s1;
        adst[(size_t)(r0 + r) * 4 + h] = s2;
      }
    }
  }
}

// ------- per-node aggregation, H=4 C=32, 64-edge chunks, fused bias+BN+ELU -------
__global__ __launch_bounds__(128) void agg128_k(
    const int* __restrict__ row_ofs, const unsigned* __restrict__ recAE,
    const int* __restrict__ recSrc, const __half* __restrict__ xp,
    const float* __restrict__ asrc, const float* __restrict__ adst,
    const float* __restrict__ bias, const float* __restrict__ g,
    const float* __restrict__ be, const float* __restrict__ rm,
    const float* __restrict__ rv, float* __restrict__ out) {
  int n = blockIdx.x;
  int t = threadIdx.x;
  int h = t >> 5, j = t & 31;
  int e4 = t >> 4, gg = t & 15;
  int hh = gg >> 2;  // head owning channels gg*8..gg*8+7
  __shared__ float s_w[4 * 64];
  __shared__ int s_src[64];
  __shared__ float sf[4], sden[4];
  __shared__ float sacc[8][132];
  int beg = row_ofs[n], end = row_ofs[n + 1];
  float adn = adst[(size_t)n * 4 + h];
  float m_run = -1e30f, s_run = 0.f;
  float acc[8];
#pragma unroll
  for (int i = 0; i < 8; ++i) acc[i] = 0.f;

  for (int base = beg; base < end; base += 64) {
    int cnt = end - base; if (cnt > 64) cnt = 64;
    // ---- alpha phase ----
    float a0 = -1e30f, a1 = -1e30f;
    if (j < cnt) {
      int idx = base + j;
      float ae = upkh(recAE[(size_t)idx * 2 + (h >> 1)], h & 1);
      int sj = recSrc[idx];
      if (h == 0) s_src[j] = sj;
      float a = asrc[(size_t)sj * 4 + h] + adn + ae;
      a0 = (a > 0.f) ? a : NEG_SLOPE * a;
    }
    if (j + 32 < cnt) {
      int idx = base + j + 32;
      float ae = upkh(recAE[(size_t)idx * 2 + (h >> 1)], h & 1);
      int sj = recSrc[idx];
      if (h == 0) s_src[j + 32] = sj;
      float a = asrc[(size_t)sj * 4 + h] + adn + ae;
      a1 = (a > 0.f) ? a : NEG_SLOPE * a;
    }
    float cm = fmaxf(a0, a1);
#pragma unroll
    for (int off = 16; off; off >>= 1) cm = fmaxf(cm, __shfl_xor(cm, off, 32));
    float f = 1.f;
    if (cm > m_run) { f = expf(m_run - cm); s_run *= f; m_run = cm; }
    if (j == 0) sf[h] = f;
    float ex0 = (j < cnt) ? expf(a0 - m_run) : 0.f;
    float ex1 = (j + 32 < cnt) ? expf(a1 - m_run) : 0.f;
    s_w[h * 64 + j] = ex0;
    s_w[h * 64 + j + 32] = ex1;
    float se = ex0 + ex1;
#pragma unroll
    for (int off = 16; off; off >>= 1) se += __shfl_xor(se, off, 32);
    s_run += se;
    __syncthreads();
    // ---- accumulate phase: 16 edges in flight (2 independent loads/thread) ----
    float ff = sf[hh];
    if (ff != 1.f) {
#pragma unroll
      for (int i = 0; i < 8; ++i) acc[i] *= ff;
    }
    for (int e2 = 0; e2 < cnt; e2 += 16) {
      int ed0 = e2 + e4, ed1 = e2 + e4 + 8;
      bool b0 = ed0 < cnt, b1 = ed1 < cnt;
      uint4 v0, v1;
      float w0 = 0.f, w1 = 0.f;
      if (b0) {
        int s0 = s_src[ed0]; w0 = s_w[hh * 64 + ed0];
        v0 = *(const uint4*)&xp[(size_t)s0 * 128 + gg * 8];
      }
      if (b1) {
        int s1 = s_src[ed1]; w1 = s_w[hh * 64 + ed1];
        v1 = *(const uint4*)&xp[(size_t)s1 * 128 + gg * 8];
      }
      if (b0) {
        acc[0] += w0 * upkh(v0.x, 0); acc[1] += w0 * upkh(v0.x, 1);
        acc[2] += w0 * upkh(v0.y, 0); acc[3] += w0 * upkh(v0.y, 1);
        acc[4] += w0 * upkh(v0.z, 0); acc[5] += w0 * upkh(v0.z, 1);
        acc[6] += w0 * upkh(v0.w, 0); acc[7] += w0 * upkh(v0.w, 1);
      }
      if (b1) {
        acc[0] += w1 * upkh(v1.x, 0); acc[1] += w1 * upkh(v1.x, 1);
        acc[2] += w1 * upkh(v1.y, 0); acc[3] += w1 * upkh(v1.y, 1);
        acc[4] += w1 * upkh(v1.z, 0); acc[5] += w1 * upkh(v1.z, 1);
        acc[6] += w1 * upkh(v1.w, 0); acc[7] += w1 * upkh(v1.w, 1);
      }
    }
    __syncthreads();
  }
  if (j == 0) sden[h] = s_run;
#pragma unroll
  for (int i = 0; i < 8; ++i) sacc[e4][gg * 8 + i] = acc[i];
  __syncthreads();
  float v = 0.f;
#pragma unroll
  for (int i = 0; i < 8; ++i) v += sacc[i][t];
  v = v / (sden[t >> 5] + 1e-16f) + bias[t];
  v = (v - rm[t]) * (g[t] * rsqrtf(rv[t] + BN_EPS)) + be[t];
  v = (v > 0.f) ? v : (expf(v) - 1.f);
  out[(size_t)n * 128 + t] = v;
}

// ---------------- layer 3 projection + alphas ----------------
__global__ __launch_bounds__(256) void xp3_k(const float* __restrict__ h2,
                                             const float* __restrict__ W3,
                                             const float* __restrict__ as3,
                                             const float* __restrict__ ad3,
                                             float* __restrict__ xp3,
                                             float* __restrict__ asrc3,
                                             float* __restrict__ adst3) {
  __shared__ float sW[256];
  int t = threadIdx.x;
  sW[t] = W3[t];
  __syncthreads();
  int n = blockIdx.x * 256 + t;
  if (n < NN) {
    const float4* row = (const float4*)(h2 + (size_t)n * 128);
    float y0 = 0.f, y1 = 0.f;
#pragma unroll
    for (int i = 0; i < 32; ++i) {
      float4 v = row[i];
      y0 += v.x * sW[(i * 4 + 0) * 2] + v.y * sW[(i * 4 + 1) * 2] +
            v.z * sW[(i * 4 + 2) * 2] + v.w * sW[(i * 4 + 3) * 2];
      y1 += v.x * sW[(i * 4 + 0) * 2 + 1] + v.y * sW[(i * 4 + 1) * 2 + 1] +
            v.z * sW[(i * 4 + 2) * 2 + 1] + v.w * sW[(i * 4 + 3) * 2 + 1];
    }
    xp3[n * 2] = y0;
    xp3[n * 2 + 1] = y1;
    asrc3[n] = y0 * as3[0] + y1 * as3[1];
    adst3[n] = y0 * ad3[0] + y1 * ad3[1];
  }
}

// ---------------- layer 3 aggregation: wave per node ----------------
__global__ __launch_bounds__(256) void agg2_k(const int* __restrict__ row_ofs,
                                              const float* __restrict__ rec3,
                                              const int* __restrict__ recSrc,
                                              const float* __restrict__ xp3,
                                              const float* __restrict__ asrc3,
                                              const float* __restrict__ adst3,
                                              const float* __restrict__ b3,
                                              float* __restrict__ out) {
  int t = threadIdx.x;
  int w = t >> 6, l = t & 63;
  int n = blockIdx.x * 4 + w;
  if (n >= NN) return;
  int beg = row_ofs[n], end = row_ofs[n + 1];
  float adn = adst3[n];
  float m = -1e30f, s = 0.f, a0 = 0.f, a1 = 0.f;
  for (int idx = beg + l; idx < end; idx += 64) {
    float aev = rec3[idx];
    int sj = recSrc[idx];
    float a = asrc3[sj] + adn + aev;
    a = (a > 0.f) ? a : NEG_SLOPE * a;
    if (a > m) {
      float f = expf(m - a);
      s *= f; a0 *= f; a1 *= f; m = a;
    }
    float ex = expf(a - m);
    s += ex;
    a0 += ex * xp3[sj * 2];
    a1 += ex * xp3[sj * 2 + 1];
  }
  float M = m;
#pragma unroll
  for (int off = 32; off; off >>= 1) M = fmaxf(M, __shfl_xor(M, off, 64));
  float f = expf(m - M);
  s *= f; a0 *= f; a1 *= f;
#pragma unroll
  for (int off = 32; off; off >>= 1) {
    s += __shfl_xor(s, off, 64);
    a0 += __shfl_xor(a0, off, 64);
    a1 += __shfl_xor(a1, off, 64);
  }
  if (l == 0) {
    float inv = 1.f / (s + 1e-16f);
    out[n * 2] = a0 * inv + b3[0];
    out[n * 2 + 1] = a1 * inv + b3[1];
  }
}

// ---------------- launcher ----------------
extern "C" void kernel_launch(void* const* d_in, const int* in_sizes, int n_in,
                              void* d_out, int out_size, void* d_ws, size_t ws_size,
                              hipStream_t stream) {
  const float* x   = (const float*)d_in[0];
  const int*   ei  = (const int*)d_in[1];
  const float* ea  = (const float*)d_in[2];
  const float* W1  = (const float*)d_in[3];
  const float* as1 = (const float*)d_in[4];
  const float* ad1 = (const float*)d_in[5];
  const float* We1 = (const float*)d_in[6];
  const float* ae1 = (const float*)d_in[7];
  const float* b1  = (const float*)d_in[8];
  const float* g1  = (const float*)d_in[9];
  const float* be1 = (const float*)d_in[10];
  const float* rm1 = (const float*)d_in[11];
  const float* rv1 = (const float*)d_in[12];
  const float* W2  = (const float*)d_in[13];
  const float* as2 = (const float*)d_in[14];
  const float* ad2 = (const float*)d_in[15];
  const float* We2 = (const float*)d_in[16];
  const float* ae2 = (const float*)d_in[17];
  const float* b2  = (const float*)d_in[18];
  const float* g2  = (const float*)d_in[19];
  const float* be2 = (const float*)d_in[20];
  const float* rm2 = (const float*)d_in[21];
  const float* rv2 = (const float*)d_in[22];
  const float* W3  = (const float*)d_in[23];
  const float* as3 = (const float*)d_in[24];
  const float* ad3 = (const float*)d_in[25];
  const float* We3 = (const float*)d_in[26];
  const float* ae3 = (const float*)d_in[27];
  const float* b3  = (const float*)d_in[28];

  const int* srcA = ei;
  const int* dstA = ei + EE;

  char* p = (char*)d_ws;
  auto alloc = [&](size_t bytes) -> void* {
    void* r = (void*)p;
    p += (bytes + 255) & ~(size_t)255;
    return r;
  };
  uint2* recAE1 = (uint2*)alloc(sizeof(uint2) * (size_t)ETOT);
  uint2* recAE2 = (uint2*)alloc(sizeof(uint2) * (size_t)ETOT);
  float* rec3   = (float*)alloc(sizeof(float) * (size_t)ETOT);
  int*   recSrc = (int*)alloc(sizeof(int) * (size_t)ETOT);
  uint2* pairs  = (uint2*)alloc(sizeof(uint2) * (size_t)EE);
  __half* xp    = (__half*)alloc(sizeof(__half) * (size_t)NN * 128);
  float* hbuf   = (float*)alloc(sizeof(float) * (size_t)NN * 128);
  float* Mbuf   = (float*)alloc(sizeof(float) * 144);
  float* meanp  = (float*)alloc(sizeof(float) * (size_t)PAY_BLOCKS * 16);
  float* asl    = (float*)alloc(sizeof(float) * 12);
  float* asrc   = (float*)alloc(sizeof(float) * (size_t)NN * 4);
  float* adst   = (float*)alloc(sizeof(float) * (size_t)NN * 4);
  float* xp3    = (float*)alloc(sizeof(float) * (size_t)NN * 2);
  float* asrc3  = (float*)alloc(sizeof(float) * (size_t)NN);
  float* adst3  = (float*)alloc(sizeof(float) * (size_t)NN);
  int* bucketCnt = (int*)alloc(sizeof(int) * (size_t)NBUCK);
  int* pBase    = (int*)alloc(sizeof(int) * (size_t)(NBUCK + 1));
  int* rBase    = (int*)alloc(sizeof(int) * (size_t)(NBUCK + 1));
  int* bcur     = (int*)alloc(sizeof(int) * (size_t)NBUCK);
  int* row_ofs  = (int*)alloc(sizeof(int) * (size_t)(NN + 1));

  hipMemsetAsync(bucketCnt, 0, NBUCK * sizeof(int), stream);

  compute_M_k<<<1, 64, 0, stream>>>(We1, ae1, We2, ae2, We3, ae3, Mbuf);
  bcount_k<<<PAY_BLOCKS, 256, 0, stream>>>(dstA, ea, bucketCnt, meanp);
  selfloop_k<<<1, 256, 0, stream>>>(meanp, Mbuf, asl);
  bscan_k<<<1, 1024, 0, stream>>>(bucketCnt, pBase, rBase, bcur);
  bscat_k<<<200, 256, 0, stream>>>(dstA, srcA, bcur, pairs);
  cbuild_k<<<NBUCK, 256, 0, stream>>>(pBase, rBase, pairs, ea, Mbuf, asl,
                                      recAE1, recAE2, rec3, recSrc, row_ofs);

  // ---- layer 1 ----
  gemm128a_k<<<dim3((NN + 63) / 64, 2), 256, 0, stream>>>(x, W1, as1, ad1, xp, asrc, adst, NN);
  agg128_k<<<NN, 128, 0, stream>>>(row_ofs, (const unsigned*)recAE1, recSrc, xp,
                                   asrc, adst, b1, g1, be1, rm1, rv1, hbuf);
  // ---- layer 2 ----
  gemm128a_k<<<dim3((NN + 63) / 64, 2), 256, 0, stream>>>(hbuf, W2, as2, ad2, xp, asrc, adst, NN);
  agg128_k<<<NN, 128, 0, stream>>>(row_ofs, (const unsigned*)recAE2, recSrc, xp,
                                   asrc, adst, b2, g2, be2, rm2, rv2, hbuf);
  // ---- layer 3 ----
  xp3_k<<<(NN + 255) / 256, 256, 0, stream>>>(hbuf, W3, as3, ad3, xp3, asrc3, adst3);
  agg2_k<<<(NN + 3) / 4, 256, 0, stream>>>(row_ofs, rec3, recSrc, xp3, asrc3, adst3,
                                           b3, (float*)d_out);
}

// Round 12
// 392.237 us; speedup vs baseline: 1.0425x; 1.0425x over previous
//
#include <hip/hip_runtime.h>
#include <hip/hip_fp16.h>
#include <math.h>

#define NN 50000
#define EE 1600000
#define ETOT (EE + NN)
#define NEG_SLOPE 0.2f
#define BN_EPS 1e-5f
#define PAY_BLOCKS 1024
#define NPB 64                        // nodes per bucket
#define NBUCK ((NN + NPB - 1) / NPB)  // 782
#define CHUNK 8192                    // edges per bscat chunk
#define NCHUNK ((EE + CHUNK - 1) / CHUNK)

// pairs[i] (bucket-grouped, 8B): {x = (dst_local<<21) | eid, y = src}
// CSR-order split arrays: recAE1 (uint2), recAE2 (uint2), rec3 (f32), recSrc (i32)
// cbuild: LDS-staged tiles — quad-coalesced ea loads, thread-per-edge compute + 64-lane stores.

static __device__ inline unsigned pkh2(float a, float b) {
  __half ha = __float2half_rn(a), hb = __float2half_rn(b);
  unsigned short ua = *(unsigned short*)&ha, ub = *(unsigned short*)&hb;
  return ((unsigned)ub << 16) | ua;
}
static __device__ inline float upkh(unsigned u, int hi) {
  unsigned short s = hi ? (unsigned short)(u >> 16) : (unsigned short)(u & 0xffff);
  __half h = *(__half*)&s;
  return __half2float(h);
}

// ---------------- M[d,h] = sum_c We[d, h*32+c] * ae[h,c] (per layer) ----------------
__global__ void compute_M_k(const float* __restrict__ We1, const float* __restrict__ ae1,
                            const float* __restrict__ We2, const float* __restrict__ ae2,
                            const float* __restrict__ We3, const float* __restrict__ ae3,
                            float* __restrict__ M) {
  int t = threadIdx.x;
  if (t < 64) {
    int d = t >> 2, h = t & 3;
    float s1 = 0.f, s2 = 0.f;
    for (int c = 0; c < 32; ++c) {
      s1 += We1[d * 128 + h * 32 + c] * ae1[h * 32 + c];
      s2 += We2[d * 128 + h * 32 + c] * ae2[h * 32 + c];
    }
    M[t] = s1;
    M[64 + t] = s2;
  }
  if (t < 16) {
    M[128 + t] = We3[t * 2] * ae3[0] + We3[t * 2 + 1] * ae3[1];
  }
}

// ---- bcount: fused dst bucket-histogram + ea mean partials (one ea stream) ----
__global__ __launch_bounds__(256) void bcount_k(const int* __restrict__ dst,
                                                const float* __restrict__ ea,
                                                int* __restrict__ bucketCnt,
                                                float* __restrict__ mean_part) {
  __shared__ int hist[1024];
  int t = threadIdx.x;
  for (int b = t; b < 1024; b += 256) hist[b] = 0;
  __syncthreads();
  float macc[16];
#pragma unroll
  for (int d = 0; d < 16; ++d) macc[d] = 0.f;
  for (int e = blockIdx.x * 256 + t; e < EE; e += PAY_BLOCKS * 256) {
    const float4* p = (const float4*)(ea + (size_t)e * 16);
    float4 q0 = p[0], q1 = p[1], q2 = p[2], q3 = p[3];
    macc[0] += q0.x; macc[1] += q0.y; macc[2] += q0.z; macc[3] += q0.w;
    macc[4] += q1.x; macc[5] += q1.y; macc[6] += q1.z; macc[7] += q1.w;
    macc[8] += q2.x; macc[9] += q2.y; macc[10] += q2.z; macc[11] += q2.w;
    macc[12] += q3.x; macc[13] += q3.y; macc[14] += q3.z; macc[15] += q3.w;
    atomicAdd(&hist[dst[e] >> 6], 1);
  }
#pragma unroll
  for (int d = 0; d < 16; ++d) {
#pragma unroll
    for (int off = 32; off; off >>= 1) macc[d] += __shfl_xor(macc[d], off, 64);
  }
  __shared__ float swsum[4][16];
  int w = t >> 6, l = t & 63;
  if (l == 0) {
#pragma unroll
    for (int d = 0; d < 16; ++d) swsum[w][d] = macc[d];
  }
  __syncthreads();
  if (t < 16) {
    mean_part[(size_t)blockIdx.x * 16 + t] =
        swsum[0][t] + swsum[1][t] + swsum[2][t] + swsum[3][t];
  }
  for (int b = t; b < NBUCK; b += 256)
    if (hist[b]) atomicAdd(&bucketCnt[b], hist[b]);
}

// -------- reduce mean partials -> asl[0..3]=L1, [4..7]=L2, [8]=L3 --------
__global__ __launch_bounds__(256) void selfloop_k(const float* __restrict__ mean_part,
                                                  const float* __restrict__ M,
                                                  float* __restrict__ alpha_sl) {
  __shared__ float s[256];
  int t = threadIdx.x;
  int d = t & 15, c = t >> 4;
  float v = 0.f;
  for (int i = c * 64; i < (c + 1) * 64; ++i) v += mean_part[(size_t)i * 16 + d];
  s[t] = v;
  __syncthreads();
  if (t < 16) {
    float sum = 0.f;
    for (int c2 = 0; c2 < 16; ++c2) sum += s[c2 * 16 + t];
    s[t] = sum / (float)EE;
  }
  __syncthreads();
  if (t < 9) {
    float r = 0.f;
    if (t < 4) {
      for (int dd = 0; dd < 16; ++dd) r += s[dd] * M[dd * 4 + t];
    } else if (t < 8) {
      int h = t - 4;
      for (int dd = 0; dd < 16; ++dd) r += s[dd] * M[64 + dd * 4 + h];
    } else {
      for (int dd = 0; dd < 16; ++dd) r += s[dd] * M[128 + dd];
    }
    alpha_sl[t] = r;
  }
}

// ---- scan NBUCK bucket totals -> pairs bases (pBase/bcur) and row bases (rBase) ----
__global__ __launch_bounds__(1024) void bscan_k(const int* __restrict__ bucketCnt,
                                                int* __restrict__ pBase,
                                                int* __restrict__ rBase,
                                                int* __restrict__ bcur) {
  __shared__ int s1[1024], s2[1024];
  int t = threadIdx.x;
  int cnt = (t < NBUCK) ? bucketCnt[t] : 0;
  int nn = 0;
  if (t < NBUCK) {
    int n0 = t * NPB;
    nn = NN - n0; if (nn > NPB) nn = NPB;
  }
  s1[t] = cnt;
  s2[t] = cnt + nn;
  __syncthreads();
  for (int off = 1; off < 1024; off <<= 1) {
    int a = (t >= off) ? s1[t - off] : 0;
    int b = (t >= off) ? s2[t - off] : 0;
    __syncthreads();
    s1[t] += a; s2[t] += b;
    __syncthreads();
  }
  if (t < NBUCK) {
    pBase[t] = s1[t] - cnt;
    rBase[t] = s2[t] - (cnt + nn);
    bcur[t] = s1[t] - cnt;
  }
  if (t == 0) { pBase[NBUCK] = EE; rBase[NBUCK] = ETOT; }
}

// ---- bucket scatter: per-chunk LDS histogram -> run reservation -> packed 8B writes ----
__global__ __launch_bounds__(256) void bscat_k(const int* __restrict__ dst,
                                               const int* __restrict__ src,
                                               int* __restrict__ bcur,
                                               uint2* __restrict__ pairs) {
  __shared__ int hist[1024];
  __shared__ int ofs[1024];
  int t = threadIdx.x;
  for (int c = blockIdx.x; c < NCHUNK; c += gridDim.x) {
    int cb = c * CHUNK;
    for (int b = t; b < 1024; b += 256) hist[b] = 0;
    __syncthreads();
#pragma unroll
    for (int k = 0; k < 8; ++k) {
      int e = cb + k * 1024 + t * 4;
      if (e < EE) {
        int4 d4 = *(const int4*)&dst[e];
        atomicAdd(&hist[d4.x >> 6], 1);
        atomicAdd(&hist[d4.y >> 6], 1);
        atomicAdd(&hist[d4.z >> 6], 1);
        atomicAdd(&hist[d4.w >> 6], 1);
      }
    }
    __syncthreads();
    for (int b = t; b < NBUCK; b += 256) {
      int h = hist[b];
      ofs[b] = h ? atomicAdd(&bcur[b], h) : 0;
      hist[b] = 0;
    }
    __syncthreads();
#pragma unroll
    for (int k = 0; k < 8; ++k) {
      int e = cb + k * 1024 + t * 4;
      if (e < EE) {
        int4 d4 = *(const int4*)&dst[e];
        int4 s4 = *(const int4*)&src[e];
        int dd[4] = {d4.x, d4.y, d4.z, d4.w};
        int sv[4] = {s4.x, s4.y, s4.z, s4.w};
#pragma unroll
        for (int j = 0; j < 4; ++j) {
          int b = dd[j] >> 6;
          int pos = ofs[b] + atomicAdd(&hist[b], 1);
          pairs[pos] = make_uint2(((unsigned)(dd[j] & (NPB - 1)) << 21) | (unsigned)(e + j),
                                  (unsigned)sv[j]);
        }
      }
    }
    __syncthreads();
  }
}

// ---- CSR build: one block/bucket; LDS-staged ea tiles; thread-per-edge stores ----
__global__ __launch_bounds__(256) void cbuild_k(const int* __restrict__ pBase,
                                                const int* __restrict__ rBase,
                                                const uint2* __restrict__ pairs,
                                                const float* __restrict__ ea,
                                                const float* __restrict__ M,
                                                const float* __restrict__ asl,
                                                uint2* __restrict__ recAE1,
                                                uint2* __restrict__ recAE2,
                                                float* __restrict__ rec3,
                                                int* __restrict__ recSrc,
                                                int* __restrict__ row_ofs) {
  __shared__ float sM[144];
  __shared__ int lcnt[NPB];
  __shared__ int ss[NPB];
  __shared__ int cur[NPB];
  __shared__ float sEA[256 * 17];
  __shared__ uint2 sPr[256];
  int b = blockIdx.x;
  int t = threadIdx.x;
  if (t < 144) sM[t] = M[t];
  if (t < NPB) lcnt[t] = 0;
  __syncthreads();
  int n0 = b * NPB;
  int n1 = n0 + NPB; if (n1 > NN) n1 = NN;
  int nn = n1 - n0;
  int pb = pBase[b], pe = pBase[b + 1];
  for (int i = pb + t; i < pe; i += 256) atomicAdd(&lcnt[pairs[i].x >> 21], 1);
  __syncthreads();
  int v = (t < nn) ? (lcnt[t] + 1) : 0;
  if (t < NPB) ss[t] = v;
  __syncthreads();
  for (int off = 1; off < NPB; off <<= 1) {
    int a = (t >= off && t < NPB) ? ss[t - off] : 0;
    __syncthreads();
    if (t < NPB) ss[t] += a;
    __syncthreads();
  }
  int rb = rBase[b];
  if (t < nn) {
    int self = rb + ss[t] - v;  // exclusive prefix
    row_ofs[n0 + t] = self;
    cur[t] = self + 1;          // slot self reserved for the self loop
    recAE1[self] = make_uint2(pkh2(asl[0], asl[1]), pkh2(asl[2], asl[3]));
    recAE2[self] = make_uint2(pkh2(asl[4], asl[5]), pkh2(asl[6], asl[7]));
    rec3[self] = asl[8];
    recSrc[self] = n0 + t;
  }
  if (b == NBUCK - 1 && t == 0) row_ofs[NN] = ETOT;
  __syncthreads();

  // ---- edge tiles: quad-coalesced ea loads into LDS, thread-per-edge compute+store ----
  int qid = t >> 2;   // 0..63
  int l = t & 3;
  for (int base2 = pb; base2 < pe; base2 += 256) {
    int cnt = pe - base2; if (cnt > 256) cnt = 256;
    // load phase
#pragma unroll
    for (int k = 0; k < 4; ++k) {
      int r = k * 64 + qid;
      if (r < cnt) {
        uint2 u = pairs[base2 + r];   // quad-broadcast
        if (l == 0) sPr[r] = u;
        float4 q = *(const float4*)(ea + (size_t)(u.x & 0x1FFFFF) * 16 + l * 4);
        int o = r * 17 + l * 4;
        sEA[o + 0] = q.x; sEA[o + 1] = q.y; sEA[o + 2] = q.z; sEA[o + 3] = q.w;
      }
    }
    __syncthreads();
    // compute + store phase (64-lane coalescable stores)
    if (t < cnt) {
      uint2 u = sPr[t];
      float a1[4] = {0.f, 0.f, 0.f, 0.f}, a2[4] = {0.f, 0.f, 0.f, 0.f};
      float a3 = 0.f;
#pragma unroll
      for (int d = 0; d < 16; ++d) {
        float vv = sEA[t * 17 + d];
#pragma unroll
        for (int h = 0; h < 4; ++h) {
          a1[h] += vv * sM[d * 4 + h];
          a2[h] += vv * sM[64 + d * 4 + h];
        }
        a3 += vv * sM[128 + d];
      }
      int pos = atomicAdd(&cur[u.x >> 21], 1);
      recAE1[pos] = make_uint2(pkh2(a1[0], a1[1]), pkh2(a1[2], a1[3]));
      recAE2[pos] = make_uint2(pkh2(a2[0], a2[1]), pkh2(a2[2], a2[3]));
      rec3[pos] = a3;
      recSrc[pos] = (int)u.y;
    }
    __syncthreads();
  }
}

// ---- GEMM 64x64 tiles + fused alpha epilogue; Y written as fp16 ----
__global__ __launch_bounds__(256) void gemm128a_k(const float* __restrict__ X,
                                                  const float* __restrict__ W,
                                                  const float* __restrict__ as,
                                                  const float* __restrict__ ad,
                                                  __half* __restrict__ Y,
                                                  float* __restrict__ asrc,
                                                  float* __restrict__ adst,
                                                  int nrows) {
  __shared__ float sW[128 * 64];
  __shared__ float sX[64 * 132];
  __shared__ float sas[128], sad[128];
  int t = threadIdx.x;
  int r0 = blockIdx.x * 64;
  int cb = blockIdx.y;  // column half: heads 2*cb, 2*cb+1
  if (t < 128) { sas[t] = as[t]; sad[t] = ad[t]; }
#pragma unroll
  for (int i = 0; i < 8; ++i) {
    int flat = t + i * 256;          // float4 index over 128x64 tile
    int k = flat >> 4, c4 = flat & 15;
    *(float4*)&sW[k * 64 + c4 * 4] = *(const float4*)&W[k * 128 + cb * 64 + c4 * 4];
  }
  int rows = nrows - r0; if (rows > 64) rows = 64;
#pragma unroll
  for (int i = 0; i < 8; ++i) {
    int flat = t + i * 256;          // float4 index over 64x128 tile
    int r = flat >> 5, k4 = flat & 31;
    if (r < rows)
      *(float4*)&sX[r * 132 + k4 * 4] = *(const float4*)&X[(size_t)(r0 + r) * 128 + k4 * 4];
  }
  __syncthreads();
  int cq = t & 15, rl = t >> 4;
  float4 acc[4];
#pragma unroll
  for (int i = 0; i < 4; ++i) acc[i] = make_float4(0.f, 0.f, 0.f, 0.f);

  for (int k = 0; k < 128; k += 4) {
    float4 w0 = *(float4*)&sW[(k + 0) * 64 + cq * 4];
    float4 w1 = *(float4*)&sW[(k + 1) * 64 + cq * 4];
    float4 w2 = *(float4*)&sW[(k + 2) * 64 + cq * 4];
    float4 w3 = *(float4*)&sW[(k + 3) * 64 + cq * 4];
#pragma unroll
    for (int i = 0; i < 4; ++i) {
      float4 xv = *(float4*)&sX[(rl + i * 16) * 132 + k];
      acc[i].x += xv.x * w0.x + xv.y * w1.x + xv.z * w2.x + xv.w * w3.x;
      acc[i].y += xv.x * w0.y + xv.y * w1.y + xv.z * w2.y + xv.w * w3.y;
      acc[i].z += xv.x * w0.z + xv.y * w1.z + xv.z * w2.z + xv.w * w3.z;
      acc[i].w += xv.x * w0.w + xv.y * w1.w + xv.z * w2.w + xv.w * w3.w;
    }
  }
  int h = cb * 2 + (cq >> 3);
  int col0 = cb * 64 + cq * 4;
#pragma unroll
  for (int i = 0; i < 4; ++i) {
    int r = rl + i * 16;
    if (r < rows) {
      uint2 st;
      st.x = pkh2(acc[i].x, acc[i].y);
      st.y = pkh2(acc[i].z, acc[i].w);
      *(uint2*)&Y[(size_t)(r0 + r) * 128 + col0] = st;
      float s1 = acc[i].x * sas[col0] + acc[i].y * sas[col0 + 1] +
                 acc[i].z * sas[col0 + 2] + acc[i].w * sas[col0 + 3];
      float s2 = acc[i].x * sad[col0] + acc[i].y * sad[col0 + 1] +
                 acc[i].z * sad[col0 + 2] + acc[i].w * sad[col0 + 3];
      s1 += __shfl_xor(s1, 1, 8); s1 += __shfl_xor(s1, 2, 8); s1 += __shfl_xor(s1, 4, 8);
      s2 += __shfl_xor(s2, 1, 8); s2 += __shfl_xor(s2, 2, 8); s2 += __shfl_xor(s2, 4, 8);
      if ((cq & 7) == 0) {
        asrc[(size_t)(r0 + r) * 4 + h] = s1;
        adst[(size_t)(r0 + r) * 4 + h] = s2;
      }
    }
  }
}

// ------- per-node aggregation, H=4 C=32, 64-edge chunks, fused bias+BN+ELU -------
__global__ __launch_bounds__(128) void agg128_k(
    const int* __restrict__ row_ofs, const unsigned* __restrict__ recAE,
    const int* __restrict__ recSrc, const __half* __restrict__ xp,
    const float* __restrict__ asrc, const float* __restrict__ adst,
    const float* __restrict__ bias, const float* __restrict__ g,
    const float* __restrict__ be, const float* __restrict__ rm,
    const float* __restrict__ rv, float* __restrict__ out) {
  int n = blockIdx.x;
  int t = threadIdx.x;
  int h = t >> 5, j = t & 31;
  int e4 = t >> 4, gg = t & 15;
  int hh = gg >> 2;  // head owning channels gg*8..gg*8+7
  __shared__ float s_w[4 * 64];
  __shared__ int s_src[64];
  __shared__ float sf[4], sden[4];
  __shared__ float sacc[8][132];
  int beg = row_ofs[n], end = row_ofs[n + 1];
  float adn = adst[(size_t)n * 4 + h];
  float m_run = -1e30f, s_run = 0.f;
  float acc[8];
#pragma unroll
  for (int i = 0; i < 8; ++i) acc[i] = 0.f;

  for (int base = beg; base < end; base += 64) {
    int cnt = end - base; if (cnt > 64) cnt = 64;
    // ---- alpha phase ----
    float a0 = -1e30f, a1 = -1e30f;
    if (j < cnt) {
      int idx = base + j;
      float ae = upkh(recAE[(size_t)idx * 2 + (h >> 1)], h & 1);
      int sj = recSrc[idx];
      if (h == 0) s_src[j] = sj;
      float a = asrc[(size_t)sj * 4 + h] + adn + ae;
      a0 = (a > 0.f) ? a : NEG_SLOPE * a;
    }
    if (j + 32 < cnt) {
      int idx = base + j + 32;
      float ae = upkh(recAE[(size_t)idx * 2 + (h >> 1)], h & 1);
      int sj = recSrc[idx];
      if (h == 0) s_src[j + 32] = sj;
      float a = asrc[(size_t)sj * 4 + h] + adn + ae;
      a1 = (a > 0.f) ? a : NEG_SLOPE * a;
    }
    float cm = fmaxf(a0, a1);
#pragma unroll
    for (int off = 16; off; off >>= 1) cm = fmaxf(cm, __shfl_xor(cm, off, 32));
    float f = 1.f;
    if (cm > m_run) { f = expf(m_run - cm); s_run *= f; m_run = cm; }
    if (j == 0) sf[h] = f;
    float ex0 = (j < cnt) ? expf(a0 - m_run) : 0.f;
    float ex1 = (j + 32 < cnt) ? expf(a1 - m_run) : 0.f;
    s_w[h * 64 + j] = ex0;
    s_w[h * 64 + j + 32] = ex1;
    float se = ex0 + ex1;
#pragma unroll
    for (int off = 16; off; off >>= 1) se += __shfl_xor(se, off, 32);
    s_run += se;
    __syncthreads();
    // ---- accumulate phase: 16 edges in flight (2 independent loads/thread) ----
    float ff = sf[hh];
    if (ff != 1.f) {
#pragma unroll
      for (int i = 0; i < 8; ++i) acc[i] *= ff;
    }
    for (int e2 = 0; e2 < cnt; e2 += 16) {
      int ed0 = e2 + e4, ed1 = e2 + e4 + 8;
      bool b0 = ed0 < cnt, b1 = ed1 < cnt;
      uint4 v0, v1;
      float w0 = 0.f, w1 = 0.f;
      if (b0) {
        int s0 = s_src[ed0]; w0 = s_w[hh * 64 + ed0];
        v0 = *(const uint4*)&xp[(size_t)s0 * 128 + gg * 8];
      }
      if (b1) {
        int s1 = s_src[ed1]; w1 = s_w[hh * 64 + ed1];
        v1 = *(const uint4*)&xp[(size_t)s1 * 128 + gg * 8];
      }
      if (b0) {
        acc[0] += w0 * upkh(v0.x, 0); acc[1] += w0 * upkh(v0.x, 1);
        acc[2] += w0 * upkh(v0.y, 0); acc[3] += w0 * upkh(v0.y, 1);
        acc[4] += w0 * upkh(v0.z, 0); acc[5] += w0 * upkh(v0.z, 1);
        acc[6] += w0 * upkh(v0.w, 0); acc[7] += w0 * upkh(v0.w, 1);
      }
      if (b1) {
        acc[0] += w1 * upkh(v1.x, 0); acc[1] += w1 * upkh(v1.x, 1);
        acc[2] += w1 * upkh(v1.y, 0); acc[3] += w1 * upkh(v1.y, 1);
        acc[4] += w1 * upkh(v1.z, 0); acc[5] += w1 * upkh(v1.z, 1);
        acc[6] += w1 * upkh(v1.w, 0); acc[7] += w1 * upkh(v1.w, 1);
      }
    }
    __syncthreads();
  }
  if (j == 0) sden[h] = s_run;
#pragma unroll
  for (int i = 0; i < 8; ++i) sacc[e4][gg * 8 + i] = acc[i];
  __syncthreads();
  float v = 0.f;
#pragma unroll
  for (int i = 0; i < 8; ++i) v += sacc[i][t];
  v = v / (sden[t >> 5] + 1e-16f) + bias[t];
  v = (v - rm[t]) * (g[t] * rsqrtf(rv[t] + BN_EPS)) + be[t];
  v = (v > 0.f) ? v : (expf(v) - 1.f);
  out[(size_t)n * 128 + t] = v;
}

// ---------------- layer 3 projection + alphas ----------------
__global__ __launch_bounds__(256) void xp3_k(const float* __restrict__ h2,
                                             const float* __restrict__ W3,
                                             const float* __restrict__ as3,
                                             const float* __restrict__ ad3,
                                             float* __restrict__ xp3,
                                             float* __restrict__ asrc3,
                                             float* __restrict__ adst3) {
  __shared__ float sW[256];
  int t = threadIdx.x;
  sW[t] = W3[t];
  __syncthreads();
  int n = blockIdx.x * 256 + t;
  if (n < NN) {
    const float4* row = (const float4*)(h2 + (size_t)n * 128);
    float y0 = 0.f, y1 = 0.f;
#pragma unroll
    for (int i = 0; i < 32; ++i) {
      float4 v = row[i];
      y0 += v.x * sW[(i * 4 + 0) * 2] + v.y * sW[(i * 4 + 1) * 2] +
            v.z * sW[(i * 4 + 2) * 2] + v.w * sW[(i * 4 + 3) * 2];
      y1 += v.x * sW[(i * 4 + 0) * 2 + 1] + v.y * sW[(i * 4 + 1) * 2 + 1] +
            v.z * sW[(i * 4 + 2) * 2 + 1] + v.w * sW[(i * 4 + 3) * 2 + 1];
    }
    xp3[n * 2] = y0;
    xp3[n * 2 + 1] = y1;
    asrc3[n] = y0 * as3[0] + y1 * as3[1];
    adst3[n] = y0 * ad3[0] + y1 * ad3[1];
  }
}

// ---------------- layer 3 aggregation: wave per node ----------------
__global__ __launch_bounds__(256) void agg2_k(const int* __restrict__ row_ofs,
                                              const float* __restrict__ rec3,
                                              const int* __restrict__ recSrc,
                                              const float* __restrict__ xp3,
                                              const float* __restrict__ asrc3,
                                              const float* __restrict__ adst3,
                                              const float* __restrict__ b3,
                                              float* __restrict__ out) {
  int t = threadIdx.x;
  int w = t >> 6, l = t & 63;
  int n = blockIdx.x * 4 + w;
  if (n >= NN) return;
  int beg = row_ofs[n], end = row_ofs[n + 1];
  float adn = adst3[n];
  float m = -1e30f, s = 0.f, a0 = 0.f, a1 = 0.f;
  for (int idx = beg + l; idx < end; idx += 64) {
    float aev = rec3[idx];
    int sj = recSrc[idx];
    float a = asrc3[sj] + adn + aev;
    a = (a > 0.f) ? a : NEG_SLOPE * a;
    if (a > m) {
      float f = expf(m - a);
      s *= f; a0 *= f; a1 *= f; m = a;
    }
    float ex = expf(a - m);
    s += ex;
    a0 += ex * xp3[sj * 2];
    a1 += ex * xp3[sj * 2 + 1];
  }
  float M = m;
#pragma unroll
  for (int off = 32; off; off >>= 1) M = fmaxf(M, __shfl_xor(M, off, 64));
  float f = expf(m - M);
  s *= f; a0 *= f; a1 *= f;
#pragma unroll
  for (int off = 32; off; off >>= 1) {
    s += __shfl_xor(s, off, 64);
    a0 += __shfl_xor(a0, off, 64);
    a1 += __shfl_xor(a1, off, 64);
  }
  if (l == 0) {
    float inv = 1.f / (s + 1e-16f);
    out[n * 2] = a0 * inv + b3[0];
    out[n * 2 + 1] = a1 * inv + b3[1];
  }
}

// ---------------- launcher ----------------
extern "C" void kernel_launch(void* const* d_in, const int* in_sizes, int n_in,
                              void* d_out, int out_size, void* d_ws, size_t ws_size,
                              hipStream_t stream) {
  const float* x   = (const float*)d_in[0];
  const int*   ei  = (const int*)d_in[1];
  const float* ea  = (const float*)d_in[2];
  const float* W1  = (const float*)d_in[3];
  const float* as1 = (const float*)d_in[4];
  const float* ad1 = (const float*)d_in[5];
  const float* We1 = (const float*)d_in[6];
  const float* ae1 = (const float*)d_in[7];
  const float* b1  = (const float*)d_in[8];
  const float* g1  = (const float*)d_in[9];
  const float* be1 = (const float*)d_in[10];
  const float* rm1 = (const float*)d_in[11];
  const float* rv1 = (const float*)d_in[12];
  const float* W2  = (const float*)d_in[13];
  const float* as2 = (const float*)d_in[14];
  const float* ad2 = (const float*)d_in[15];
  const float* We2 = (const float*)d_in[16];
  const float* ae2 = (const float*)d_in[17];
  const float* b2  = (const float*)d_in[18];
  const float* g2  = (const float*)d_in[19];
  const float* be2 = (const float*)d_in[20];
  const float* rm2 = (const float*)d_in[21];
  const float* rv2 = (const float*)d_in[22];
  const float* W3  = (const float*)d_in[23];
  const float* as3 = (const float*)d_in[24];
  const float* ad3 = (const float*)d_in[25];
  const float* We3 = (const float*)d_in[26];
  const float* ae3 = (const float*)d_in[27];
  const float* b3  = (const float*)d_in[28];

  const int* srcA = ei;
  const int* dstA = ei + EE;

  char* p = (char*)d_ws;
  auto alloc = [&](size_t bytes) -> void* {
    void* r = (void*)p;
    p += (bytes + 255) & ~(size_t)255;
    return r;
  };
  uint2* recAE1 = (uint2*)alloc(sizeof(uint2) * (size_t)ETOT);
  uint2* recAE2 = (uint2*)alloc(sizeof(uint2) * (size_t)ETOT);
  float* rec3   = (float*)alloc(sizeof(float) * (size_t)ETOT);
  int*   recSrc = (int*)alloc(sizeof(int) * (size_t)ETOT);
  uint2* pairs  = (uint2*)alloc(sizeof(uint2) * (size_t)EE);
  __half* xp    = (__half*)alloc(sizeof(__half) * (size_t)NN * 128);
  float* hbuf   = (float*)alloc(sizeof(float) * (size_t)NN * 128);
  float* Mbuf   = (float*)alloc(sizeof(float) * 144);
  float* meanp  = (float*)alloc(sizeof(float) * (size_t)PAY_BLOCKS * 16);
  float* asl    = (float*)alloc(sizeof(float) * 12);
  float* asrc   = (float*)alloc(sizeof(float) * (size_t)NN * 4);
  float* adst   = (float*)alloc(sizeof(float) * (size_t)NN * 4);
  float* xp3    = (float*)alloc(sizeof(float) * (size_t)NN * 2);
  float* asrc3  = (float*)alloc(sizeof(float) * (size_t)NN);
  float* adst3  = (float*)alloc(sizeof(float) * (size_t)NN);
  int* bucketCnt = (int*)alloc(sizeof(int) * (size_t)NBUCK);
  int* pBase    = (int*)alloc(sizeof(int) * (size_t)(NBUCK + 1));
  int* rBase    = (int*)alloc(sizeof(int) * (size_t)(NBUCK + 1));
  int* bcur     = (int*)alloc(sizeof(int) * (size_t)NBUCK);
  int* row_ofs  = (int*)alloc(sizeof(int) * (size_t)(NN + 1));

  hipMemsetAsync(bucketCnt, 0, NBUCK * sizeof(int), stream);

  compute_M_k<<<1, 64, 0, stream>>>(We1, ae1, We2, ae2, We3, ae3, Mbuf);
  bcount_k<<<PAY_BLOCKS, 256, 0, stream>>>(dstA, ea, bucketCnt, meanp);
  selfloop_k<<<1, 256, 0, stream>>>(meanp, Mbuf, asl);
  bscan_k<<<1, 1024, 0, stream>>>(bucketCnt, pBase, rBase, bcur);
  bscat_k<<<200, 256, 0, stream>>>(dstA, srcA, bcur, pairs);
  cbuild_k<<<NBUCK, 256, 0, stream>>>(pBase, rBase, pairs, ea, Mbuf, asl,
                                      recAE1, recAE2, rec3, recSrc, row_ofs);

  // ---- layer 1 ----
  gemm128a_k<<<dim3((NN + 63) / 64, 2), 256, 0, stream>>>(x, W1, as1, ad1, xp, asrc, adst, NN);
  agg128_k<<<NN, 128, 0, stream>>>(row_ofs, (const unsigned*)recAE1, recSrc, xp,
                                   asrc, adst, b1, g1, be1, rm1, rv1, hbuf);
  // ---- layer 2 ----
  gemm128a_k<<<dim3((NN + 63) / 64, 2), 256, 0, stream>>>(hbuf, W2, as2, ad2, xp, asrc, adst, NN);
  agg128_k<<<NN, 128, 0, stream>>>(row_ofs, (const unsigned*)recAE2, recSrc, xp,
                                   asrc, adst, b2, g2, be2, rm2, rv2, hbuf);
  // ---- layer 3 ----
  xp3_k<<<(NN + 255) / 256, 256, 0, stream>>>(hbuf, W3, as3, ad3, xp3, asrc3, adst3);
  agg2_k<<<(NN + 3) / 4, 256, 0, stream>>>(row_ofs, rec3, recSrc, xp3, asrc3, adst3,
                                           b3, (float*)d_out);
}

// Round 13
// 376.750 us; speedup vs baseline: 1.0853x; 1.0411x over previous
//
#include <hip/hip_runtime.h>
#include <hip/hip_fp16.h>
#include <math.h>

#define NN 50000
#define EE 1600000
#define ETOT (EE + NN)
#define NEG_SLOPE 0.2f
#define BN_EPS 1e-5f
#define NPB 64                        // nodes per bucket
#define NBUCK ((NN + NPB - 1) / NPB)  // 782
#define CHUNK 8192                    // edges per bscat chunk
#define NCHUNK ((EE + CHUNK - 1) / CHUNK)

// pairs[i] (bucket-grouped, 8B): {x = (dst_local<<21) | eid, y = src}
// CSR-order split arrays: recAE1 (uint2), recAE2 (uint2), rec3 (f32), recSrc (i32)
// cbuild: LDS-staged ea tiles + fused mean partials; self-loop slots filled by slrec_k.

static __device__ inline unsigned pkh2(float a, float b) {
  __half ha = __float2half_rn(a), hb = __float2half_rn(b);
  unsigned short ua = *(unsigned short*)&ha, ub = *(unsigned short*)&hb;
  return ((unsigned)ub << 16) | ua;
}
static __device__ inline float upkh(unsigned u, int hi) {
  unsigned short s = hi ? (unsigned short)(u >> 16) : (unsigned short)(u & 0xffff);
  __half h = *(__half*)&s;
  return __half2float(h);
}

// ---------------- M[d,h] = sum_c We[d, h*32+c] * ae[h,c] (per layer) ----------------
__global__ void compute_M_k(const float* __restrict__ We1, const float* __restrict__ ae1,
                            const float* __restrict__ We2, const float* __restrict__ ae2,
                            const float* __restrict__ We3, const float* __restrict__ ae3,
                            float* __restrict__ M) {
  int t = threadIdx.x;
  if (t < 64) {
    int d = t >> 2, h = t & 3;
    float s1 = 0.f, s2 = 0.f;
    for (int c = 0; c < 32; ++c) {
      s1 += We1[d * 128 + h * 32 + c] * ae1[h * 32 + c];
      s2 += We2[d * 128 + h * 32 + c] * ae2[h * 32 + c];
    }
    M[t] = s1;
    M[64 + t] = s2;
  }
  if (t < 16) {
    M[128 + t] = We3[t * 2] * ae3[0] + We3[t * 2 + 1] * ae3[1];
  }
}

// ---- bcount: dst bucket-histogram only (int4, LDS hist) ----
__global__ __launch_bounds__(256) void bcount_k(const int* __restrict__ dst,
                                                int* __restrict__ bucketCnt) {
  __shared__ int hist[1024];
  int t = threadIdx.x;
  for (int b = t; b < 1024; b += 256) hist[b] = 0;
  __syncthreads();
  for (int e = (blockIdx.x * 256 + t) * 4; e < EE; e += gridDim.x * 1024) {
    int4 d4 = *(const int4*)&dst[e];
    atomicAdd(&hist[d4.x >> 6], 1);
    atomicAdd(&hist[d4.y >> 6], 1);
    atomicAdd(&hist[d4.z >> 6], 1);
    atomicAdd(&hist[d4.w >> 6], 1);
  }
  __syncthreads();
  for (int b = t; b < NBUCK; b += 256)
    if (hist[b]) atomicAdd(&bucketCnt[b], hist[b]);
}

// -------- reduce cbuild's mean partials -> asl[0..3]=L1, [4..7]=L2, [8]=L3 --------
__global__ __launch_bounds__(256) void selfloop_k(const float* __restrict__ mean_part,
                                                  const float* __restrict__ M,
                                                  float* __restrict__ alpha_sl) {
  __shared__ float s[256];
  int t = threadIdx.x;
  int d = t & 15, c = t >> 4;  // 16 strided chunks over NBUCK partials
  float v = 0.f;
  for (int i = c; i < NBUCK; i += 16) v += mean_part[(size_t)i * 16 + d];
  s[t] = v;
  __syncthreads();
  if (t < 16) {
    float sum = 0.f;
    for (int c2 = 0; c2 < 16; ++c2) sum += s[c2 * 16 + t];
    s[t] = sum / (float)EE;
  }
  __syncthreads();
  if (t < 9) {
    float r = 0.f;
    if (t < 4) {
      for (int dd = 0; dd < 16; ++dd) r += s[dd] * M[dd * 4 + t];
    } else if (t < 8) {
      int h = t - 4;
      for (int dd = 0; dd < 16; ++dd) r += s[dd] * M[64 + dd * 4 + h];
    } else {
      for (int dd = 0; dd < 16; ++dd) r += s[dd] * M[128 + dd];
    }
    alpha_sl[t] = r;
  }
}

// -------- fill self-loop slots at row_ofs[n] --------
__global__ __launch_bounds__(256) void slrec_k(const int* __restrict__ row_ofs,
                                               const float* __restrict__ asl,
                                               uint2* __restrict__ recAE1,
                                               uint2* __restrict__ recAE2,
                                               float* __restrict__ rec3,
                                               int* __restrict__ recSrc) {
  int n = blockIdx.x * 256 + threadIdx.x;
  if (n < NN) {
    int p = row_ofs[n];
    recAE1[p] = make_uint2(pkh2(asl[0], asl[1]), pkh2(asl[2], asl[3]));
    recAE2[p] = make_uint2(pkh2(asl[4], asl[5]), pkh2(asl[6], asl[7]));
    rec3[p] = asl[8];
    recSrc[p] = n;
  }
}

// ---- scan NBUCK bucket totals -> pairs bases (pBase/bcur) and row bases (rBase) ----
__global__ __launch_bounds__(1024) void bscan_k(const int* __restrict__ bucketCnt,
                                                int* __restrict__ pBase,
                                                int* __restrict__ rBase,
                                                int* __restrict__ bcur) {
  __shared__ int s1[1024], s2[1024];
  int t = threadIdx.x;
  int cnt = (t < NBUCK) ? bucketCnt[t] : 0;
  int nn = 0;
  if (t < NBUCK) {
    int n0 = t * NPB;
    nn = NN - n0; if (nn > NPB) nn = NPB;
  }
  s1[t] = cnt;
  s2[t] = cnt + nn;
  __syncthreads();
  for (int off = 1; off < 1024; off <<= 1) {
    int a = (t >= off) ? s1[t - off] : 0;
    int b = (t >= off) ? s2[t - off] : 0;
    __syncthreads();
    s1[t] += a; s2[t] += b;
    __syncthreads();
  }
  if (t < NBUCK) {
    pBase[t] = s1[t] - cnt;
    rBase[t] = s2[t] - (cnt + nn);
    bcur[t] = s1[t] - cnt;
  }
  if (t == 0) { pBase[NBUCK] = EE; rBase[NBUCK] = ETOT; }
}

// ---- bucket scatter: per-chunk LDS histogram -> run reservation -> packed 8B writes ----
__global__ __launch_bounds__(256) void bscat_k(const int* __restrict__ dst,
                                               const int* __restrict__ src,
                                               int* __restrict__ bcur,
                                               uint2* __restrict__ pairs) {
  __shared__ int hist[1024];
  __shared__ int ofs[1024];
  int t = threadIdx.x;
  for (int c = blockIdx.x; c < NCHUNK; c += gridDim.x) {
    int cb = c * CHUNK;
    for (int b = t; b < 1024; b += 256) hist[b] = 0;
    __syncthreads();
#pragma unroll
    for (int k = 0; k < 8; ++k) {
      int e = cb + k * 1024 + t * 4;
      if (e < EE) {
        int4 d4 = *(const int4*)&dst[e];
        atomicAdd(&hist[d4.x >> 6], 1);
        atomicAdd(&hist[d4.y >> 6], 1);
        atomicAdd(&hist[d4.z >> 6], 1);
        atomicAdd(&hist[d4.w >> 6], 1);
      }
    }
    __syncthreads();
    for (int b = t; b < NBUCK; b += 256) {
      int h = hist[b];
      ofs[b] = h ? atomicAdd(&bcur[b], h) : 0;
      hist[b] = 0;
    }
    __syncthreads();
#pragma unroll
    for (int k = 0; k < 8; ++k) {
      int e = cb + k * 1024 + t * 4;
      if (e < EE) {
        int4 d4 = *(const int4*)&dst[e];
        int4 s4 = *(const int4*)&src[e];
        int dd[4] = {d4.x, d4.y, d4.z, d4.w};
        int sv[4] = {s4.x, s4.y, s4.z, s4.w};
#pragma unroll
        for (int j = 0; j < 4; ++j) {
          int b = dd[j] >> 6;
          int pos = ofs[b] + atomicAdd(&hist[b], 1);
          pairs[pos] = make_uint2(((unsigned)(dd[j] & (NPB - 1)) << 21) | (unsigned)(e + j),
                                  (unsigned)sv[j]);
        }
      }
    }
    __syncthreads();
  }
}

// ---- CSR build: one block/bucket; LDS-staged ea tiles; fused mean partials ----
__global__ __launch_bounds__(256) void cbuild_k(const int* __restrict__ pBase,
                                                const int* __restrict__ rBase,
                                                const uint2* __restrict__ pairs,
                                                const float* __restrict__ ea,
                                                const float* __restrict__ M,
                                                uint2* __restrict__ recAE1,
                                                uint2* __restrict__ recAE2,
                                                float* __restrict__ rec3,
                                                int* __restrict__ recSrc,
                                                int* __restrict__ row_ofs,
                                                float* __restrict__ mean_part) {
  __shared__ float sM[144];
  __shared__ int lcnt[NPB];
  __shared__ int ss[NPB];
  __shared__ int cur[NPB];
  __shared__ float sEA[256 * 17];
  __shared__ uint2 sPr[256];
  __shared__ float swsum[4][16];
  int b = blockIdx.x;
  int t = threadIdx.x;
  if (t < 144) sM[t] = M[t];
  if (t < NPB) lcnt[t] = 0;
  __syncthreads();
  int n0 = b * NPB;
  int n1 = n0 + NPB; if (n1 > NN) n1 = NN;
  int nn = n1 - n0;
  int pb = pBase[b], pe = pBase[b + 1];
  for (int i = pb + t; i < pe; i += 256) atomicAdd(&lcnt[pairs[i].x >> 21], 1);
  __syncthreads();
  int v = (t < nn) ? (lcnt[t] + 1) : 0;
  if (t < NPB) ss[t] = v;
  __syncthreads();
  for (int off = 1; off < NPB; off <<= 1) {
    int a = (t >= off && t < NPB) ? ss[t - off] : 0;
    __syncthreads();
    if (t < NPB) ss[t] += a;
    __syncthreads();
  }
  int rb = rBase[b];
  if (t < nn) {
    int self = rb + ss[t] - v;  // exclusive prefix
    row_ofs[n0 + t] = self;
    cur[t] = self + 1;          // slot self reserved for the self loop (slrec_k fills it)
  }
  if (b == NBUCK - 1 && t == 0) row_ofs[NN] = ETOT;
  __syncthreads();

  // ---- edge tiles: quad-coalesced ea loads into LDS, thread-per-edge compute+store ----
  int qid = t >> 2;   // 0..63
  int l = t & 3;
  float macc[16];
#pragma unroll
  for (int d = 0; d < 16; ++d) macc[d] = 0.f;
  for (int base2 = pb; base2 < pe; base2 += 256) {
    int cnt = pe - base2; if (cnt > 256) cnt = 256;
    // load phase
#pragma unroll
    for (int k = 0; k < 4; ++k) {
      int r = k * 64 + qid;
      if (r < cnt) {
        uint2 u = pairs[base2 + r];   // quad-broadcast
        if (l == 0) sPr[r] = u;
        float4 q = *(const float4*)(ea + (size_t)(u.x & 0x1FFFFF) * 16 + l * 4);
        int o = r * 17 + l * 4;
        sEA[o + 0] = q.x; sEA[o + 1] = q.y; sEA[o + 2] = q.z; sEA[o + 3] = q.w;
      }
    }
    __syncthreads();
    // compute + store phase (64-lane coalescable stores) + mean accumulation
    if (t < cnt) {
      uint2 u = sPr[t];
      float a1[4] = {0.f, 0.f, 0.f, 0.f}, a2[4] = {0.f, 0.f, 0.f, 0.f};
      float a3 = 0.f;
#pragma unroll
      for (int d = 0; d < 16; ++d) {
        float vv = sEA[t * 17 + d];
        macc[d] += vv;
#pragma unroll
        for (int h = 0; h < 4; ++h) {
          a1[h] += vv * sM[d * 4 + h];
          a2[h] += vv * sM[64 + d * 4 + h];
        }
        a3 += vv * sM[128 + d];
      }
      int pos = atomicAdd(&cur[u.x >> 21], 1);
      recAE1[pos] = make_uint2(pkh2(a1[0], a1[1]), pkh2(a1[2], a1[3]));
      recAE2[pos] = make_uint2(pkh2(a2[0], a2[1]), pkh2(a2[2], a2[3]));
      rec3[pos] = a3;
      recSrc[pos] = (int)u.y;
    }
    __syncthreads();
  }
  // block-reduce mean partials -> mean_part[b*16 + d]
#pragma unroll
  for (int d = 0; d < 16; ++d) {
#pragma unroll
    for (int off = 32; off; off >>= 1) macc[d] += __shfl_xor(macc[d], off, 64);
  }
  int w = t >> 6, l2 = t & 63;
  if (l2 == 0) {
#pragma unroll
    for (int d = 0; d < 16; ++d) swsum[w][d] = macc[d];
  }
  __syncthreads();
  if (t < 16) {
    mean_part[(size_t)b * 16 + t] =
        swsum[0][t] + swsum[1][t] + swsum[2][t] + swsum[3][t];
  }
}

// ---- GEMM 64x64 tiles + fused alpha epilogue; Y written as fp16 ----
__global__ __launch_bounds__(256) void gemm128a_k(const float* __restrict__ X,
                                                  const float* __restrict__ W,
                                                  const float* __restrict__ as,
                                                  const float* __restrict__ ad,
                                                  __half* __restrict__ Y,
                                                  float* __restrict__ asrc,
                                                  float* __restrict__ adst,
                                                  int nrows) {
  __shared__ float sW[128 * 64];
  __shared__ float sX[64 * 132];
  __shared__ float sas[128], sad[128];
  int t = threadIdx.x;
  int r0 = blockIdx.x * 64;
  int cb = blockIdx.y;  // column half: heads 2*cb, 2*cb+1
  if (t < 128) { sas[t] = as[t]; sad[t] = ad[t]; }
#pragma unroll
  for (int i = 0; i < 8; ++i) {
    int flat = t + i * 256;          // float4 index over 128x64 tile
    int k = flat >> 4, c4 = flat & 15;
    *(float4*)&sW[k * 64 + c4 * 4] = *(const float4*)&W[k * 128 + cb * 64 + c4 * 4];
  }
  int rows = nrows - r0; if (rows > 64) rows = 64;
#pragma unroll
  for (int i = 0; i < 8; ++i) {
    int flat = t + i * 256;          // float4 index over 64x128 tile
    int r = flat >> 5, k4 = flat & 31;
    if (r < rows)
      *(float4*)&sX[r * 132 + k4 * 4] = *(const float4*)&X[(size_t)(r0 + r) * 128 + k4 * 4];
  }
  __syncthreads();
  int cq = t & 15, rl = t >> 4;
  float4 acc[4];
#pragma unroll
  for (int i = 0; i < 4; ++i) acc[i] = make_float4(0.f, 0.f, 0.f, 0.f);

  for (int k = 0; k < 128; k += 4) {
    float4 w0 = *(float4*)&sW[(k + 0) * 64 + cq * 4];
    float4 w1 = *(float4*)&sW[(k + 1) * 64 + cq * 4];
    float4 w2 = *(float4*)&sW[(k + 2) * 64 + cq * 4];
    float4 w3 = *(float4*)&sW[(k + 3) * 64 + cq * 4];
#pragma unroll
    for (int i = 0; i < 4; ++i) {
      float4 xv = *(float4*)&sX[(rl + i * 16) * 132 + k];
      acc[i].x += xv.x * w0.x + xv.y * w1.x + xv.z * w2.x + xv.w * w3.x;
      acc[i].y += xv.x * w0.y + xv.y * w1.y + xv.z * w2.y + xv.w * w3.y;
      acc[i].z += xv.x * w0.z + xv.y * w1.z + xv.z * w2.z + xv.w * w3.z;
      acc[i].w += xv.x * w0.w + xv.y * w1.w + xv.z * w2.w + xv.w * w3.w;
    }
  }
  int h = cb * 2 + (cq >> 3);
  int col0 = cb * 64 + cq * 4;
#pragma unroll
  for (int i = 0; i < 4; ++i) {
    int r = rl + i * 16;
    if (r < rows) {
      uint2 st;
      st.x = pkh2(acc[i].x, acc[i].y);
      st.y = pkh2(acc[i].z, acc[i].w);
      *(uint2*)&Y[(size_t)(r0 + r) * 128 + col0] = st;
      float s1 = acc[i].x * sas[col0] + acc[i].y * sas[col0 + 1] +
                 acc[i].z * sas[col0 + 2] + acc[i].w * sas[col0 + 3];
      float s2 = acc[i].x * sad[col0] + acc[i].y * sad[col0 + 1] +
                 acc[i].z * sad[col0 + 2] + acc[i].w * sad[col0 + 3];
      s1 += __shfl_xor(s1, 1, 8); s1 += __shfl_xor(s1, 2, 8); s1 += __shfl_xor(s1, 4, 8);
      s2 += __shfl_xor(s2, 1, 8); s2 += __shfl_xor(s2, 2, 8); s2 += __shfl_xor(s2, 4, 8);
      if ((cq & 7) == 0) {
        asrc[(size_t)(r0 + r) * 4 + h] = s1;
        adst[(size_t)(r0 + r) * 4 + h] = s2;
      }
    }
  }
}

// ------- per-node aggregation, H=4 C=32, 64-edge chunks, fused bias+BN+ELU -------
__global__ __launch_bounds__(128) void agg128_k(
    const int* __restrict__ row_ofs, const unsigned* __restrict__ recAE,
    const int* __restrict__ recSrc, const __half* __restrict__ xp,
    const float* __restrict__ asrc, const float* __restrict__ adst,
    const float* __restrict__ bias, const float* __restrict__ g,
    const float* __restrict__ be, const float* __restrict__ rm,
    const float* __restrict__ rv, float* __restrict__ out) {
  int n = blockIdx.x;
  int t = threadIdx.x;
  int h = t >> 5, j = t & 31;
  int e4 = t >> 4, gg = t & 15;
  int hh = gg >> 2;  // head owning channels gg*8..gg*8+7
  __shared__ float s_w[4 * 64];
  __shared__ int s_src[64];
  __shared__ float sf[4], sden[4];
  __shared__ float sacc[8][132];
  int beg = row_ofs[n], end = row_ofs[n + 1];
  float adn = adst[(size_t)n * 4 + h];
  float m_run = -1e30f, s_run = 0.f;
  float acc[8];
#pragma unroll
  for (int i = 0; i < 8; ++i) acc[i] = 0.f;

  for (int base = beg; base < end; base += 64) {
    int cnt = end - base; if (cnt > 64) cnt = 64;
    // ---- alpha phase ----
    float a0 = -1e30f, a1 = -1e30f;
    if (j < cnt) {
      int idx = base + j;
      float ae = upkh(recAE[(size_t)idx * 2 + (h >> 1)], h & 1);
      int sj = recSrc[idx];
      if (h == 0) s_src[j] = sj;
      float a = asrc[(size_t)sj * 4 + h] + adn + ae;
      a0 = (a > 0.f) ? a : NEG_SLOPE * a;
    }
    if (j + 32 < cnt) {
      int idx = base + j + 32;
      float ae = upkh(recAE[(size_t)idx * 2 + (h >> 1)], h & 1);
      int sj = recSrc[idx];
      if (h == 0) s_src[j + 32] = sj;
      float a = asrc[(size_t)sj * 4 + h] + adn + ae;
      a1 = (a > 0.f) ? a : NEG_SLOPE * a;
    }
    float cm = fmaxf(a0, a1);
#pragma unroll
    for (int off = 16; off; off >>= 1) cm = fmaxf(cm, __shfl_xor(cm, off, 32));
    float f = 1.f;
    if (cm > m_run) { f = expf(m_run - cm); s_run *= f; m_run = cm; }
    if (j == 0) sf[h] = f;
    float ex0 = (j < cnt) ? expf(a0 - m_run) : 0.f;
    float ex1 = (j + 32 < cnt) ? expf(a1 - m_run) : 0.f;
    s_w[h * 64 + j] = ex0;
    s_w[h * 64 + j + 32] = ex1;
    float se = ex0 + ex1;
#pragma unroll
    for (int off = 16; off; off >>= 1) se += __shfl_xor(se, off, 32);
    s_run += se;
    __syncthreads();
    // ---- accumulate phase: 16 edges in flight (2 independent loads/thread) ----
    float ff = sf[hh];
    if (ff != 1.f) {
#pragma unroll
      for (int i = 0; i < 8; ++i) acc[i] *= ff;
    }
    for (int e2 = 0; e2 < cnt; e2 += 16) {
      int ed0 = e2 + e4, ed1 = e2 + e4 + 8;
      bool b0 = ed0 < cnt, b1 = ed1 < cnt;
      uint4 v0, v1;
      float w0 = 0.f, w1 = 0.f;
      if (b0) {
        int s0 = s_src[ed0]; w0 = s_w[hh * 64 + ed0];
        v0 = *(const uint4*)&xp[(size_t)s0 * 128 + gg * 8];
      }
      if (b1) {
        int s1 = s_src[ed1]; w1 = s_w[hh * 64 + ed1];
        v1 = *(const uint4*)&xp[(size_t)s1 * 128 + gg * 8];
      }
      if (b0) {
        acc[0] += w0 * upkh(v0.x, 0); acc[1] += w0 * upkh(v0.x, 1);
        acc[2] += w0 * upkh(v0.y, 0); acc[3] += w0 * upkh(v0.y, 1);
        acc[4] += w0 * upkh(v0.z, 0); acc[5] += w0 * upkh(v0.z, 1);
        acc[6] += w0 * upkh(v0.w, 0); acc[7] += w0 * upkh(v0.w, 1);
      }
      if (b1) {
        acc[0] += w1 * upkh(v1.x, 0); acc[1] += w1 * upkh(v1.x, 1);
        acc[2] += w1 * upkh(v1.y, 0); acc[3] += w1 * upkh(v1.y, 1);
        acc[4] += w1 * upkh(v1.z, 0); acc[5] += w1 * upkh(v1.z, 1);
        acc[6] += w1 * upkh(v1.w, 0); acc[7] += w1 * upkh(v1.w, 1);
      }
    }
    __syncthreads();
  }
  if (j == 0) sden[h] = s_run;
#pragma unroll
  for (int i = 0; i < 8; ++i) sacc[e4][gg * 8 + i] = acc[i];
  __syncthreads();
  float v = 0.f;
#pragma unroll
  for (int i = 0; i < 8; ++i) v += sacc[i][t];
  v = v / (sden[t >> 5] + 1e-16f) + bias[t];
  v = (v - rm[t]) * (g[t] * rsqrtf(rv[t] + BN_EPS)) + be[t];
  v = (v > 0.f) ? v : (expf(v) - 1.f);
  out[(size_t)n * 128 + t] = v;
}

// ---------------- layer 3 projection + alphas ----------------
__global__ __launch_bounds__(256) void xp3_k(const float* __restrict__ h2,
                                             const float* __restrict__ W3,
                                             const float* __restrict__ as3,
                                             const float* __restrict__ ad3,
                                             float* __restrict__ xp3,
                                             float* __restrict__ asrc3,
                                             float* __restrict__ adst3) {
  __shared__ float sW[256];
  int t = threadIdx.x;
  sW[t] = W3[t];
  __syncthreads();
  int n = blockIdx.x * 256 + t;
  if (n < NN) {
    const float4* row = (const float4*)(h2 + (size_t)n * 128);
    float y0 = 0.f, y1 = 0.f;
#pragma unroll
    for (int i = 0; i < 32; ++i) {
      float4 v = row[i];
      y0 += v.x * sW[(i * 4 + 0) * 2] + v.y * sW[(i * 4 + 1) * 2] +
            v.z * sW[(i * 4 + 2) * 2] + v.w * sW[(i * 4 + 3) * 2];
      y1 += v.x * sW[(i * 4 + 0) * 2 + 1] + v.y * sW[(i * 4 + 1) * 2 + 1] +
            v.z * sW[(i * 4 + 2) * 2 + 1] + v.w * sW[(i * 4 + 3) * 2 + 1];
    }
    xp3[n * 2] = y0;
    xp3[n * 2 + 1] = y1;
    asrc3[n] = y0 * as3[0] + y1 * as3[1];
    adst3[n] = y0 * ad3[0] + y1 * ad3[1];
  }
}

// ---------------- layer 3 aggregation: wave per node ----------------
__global__ __launch_bounds__(256) void agg2_k(const int* __restrict__ row_ofs,
                                              const float* __restrict__ rec3,
                                              const int* __restrict__ recSrc,
                                              const float* __restrict__ xp3,
                                              const float* __restrict__ asrc3,
                                              const float* __restrict__ adst3,
                                              const float* __restrict__ b3,
                                              float* __restrict__ out) {
  int t = threadIdx.x;
  int w = t >> 6, l = t & 63;
  int n = blockIdx.x * 4 + w;
  if (n >= NN) return;
  int beg = row_ofs[n], end = row_ofs[n + 1];
  float adn = adst3[n];
  float m = -1e30f, s = 0.f, a0 = 0.f, a1 = 0.f;
  for (int idx = beg + l; idx < end; idx += 64) {
    float aev = rec3[idx];
    int sj = recSrc[idx];
    float a = asrc3[sj] + adn + aev;
    a = (a > 0.f) ? a : NEG_SLOPE * a;
    if (a > m) {
      float f = expf(m - a);
      s *= f; a0 *= f; a1 *= f; m = a;
    }
    float ex = expf(a - m);
    s += ex;
    a0 += ex * xp3[sj * 2];
    a1 += ex * xp3[sj * 2 + 1];
  }
  float M = m;
#pragma unroll
  for (int off = 32; off; off >>= 1) M = fmaxf(M, __shfl_xor(M, off, 64));
  float f = expf(m - M);
  s *= f; a0 *= f; a1 *= f;
#pragma unroll
  for (int off = 32; off; off >>= 1) {
    s += __shfl_xor(s, off, 64);
    a0 += __shfl_xor(a0, off, 64);
    a1 += __shfl_xor(a1, off, 64);
  }
  if (l == 0) {
    float inv = 1.f / (s + 1e-16f);
    out[n * 2] = a0 * inv + b3[0];
    out[n * 2 + 1] = a1 * inv + b3[1];
  }
}

// ---------------- launcher ----------------
extern "C" void kernel_launch(void* const* d_in, const int* in_sizes, int n_in,
                              void* d_out, int out_size, void* d_ws, size_t ws_size,
                              hipStream_t stream) {
  const float* x   = (const float*)d_in[0];
  const int*   ei  = (const int*)d_in[1];
  const float* ea  = (const float*)d_in[2];
  const float* W1  = (const float*)d_in[3];
  const float* as1 = (const float*)d_in[4];
  const float* ad1 = (const float*)d_in[5];
  const float* We1 = (const float*)d_in[6];
  const float* ae1 = (const float*)d_in[7];
  const float* b1  = (const float*)d_in[8];
  const float* g1  = (const float*)d_in[9];
  const float* be1 = (const float*)d_in[10];
  const float* rm1 = (const float*)d_in[11];
  const float* rv1 = (const float*)d_in[12];
  const float* W2  = (const float*)d_in[13];
  const float* as2 = (const float*)d_in[14];
  const float* ad2 = (const float*)d_in[15];
  const float* We2 = (const float*)d_in[16];
  const float* ae2 = (const float*)d_in[17];
  const float* b2  = (const float*)d_in[18];
  const float* g2  = (const float*)d_in[19];
  const float* be2 = (const float*)d_in[20];
  const float* rm2 = (const float*)d_in[21];
  const float* rv2 = (const float*)d_in[22];
  const float* W3  = (const float*)d_in[23];
  const float* as3 = (const float*)d_in[24];
  const float* ad3 = (const float*)d_in[25];
  const float* We3 = (const float*)d_in[26];
  const float* ae3 = (const float*)d_in[27];
  const float* b3  = (const float*)d_in[28];

  const int* srcA = ei;
  const int* dstA = ei + EE;

  char* p = (char*)d_ws;
  auto alloc = [&](size_t bytes) -> void* {
    void* r = (void*)p;
    p += (bytes + 255) & ~(size_t)255;
    return r;
  };
  uint2* recAE1 = (uint2*)alloc(sizeof(uint2) * (size_t)ETOT);
  uint2* recAE2 = (uint2*)alloc(sizeof(uint2) * (size_t)ETOT);
  float* rec3   = (float*)alloc(sizeof(float) * (size_t)ETOT);
  int*   recSrc = (int*)alloc(sizeof(int) * (size_t)ETOT);
  uint2* pairs  = (uint2*)alloc(sizeof(uint2) * (size_t)EE);
  __half* xp    = (__half*)alloc(sizeof(__half) * (size_t)NN * 128);
  float* hbuf   = (float*)alloc(sizeof(float) * (size_t)NN * 128);
  float* Mbuf   = (float*)alloc(sizeof(float) * 144);
  float* meanp  = (float*)alloc(sizeof(float) * (size_t)NBUCK * 16);
  float* asl    = (float*)alloc(sizeof(float) * 12);
  float* asrc   = (float*)alloc(sizeof(float) * (size_t)NN * 4);
  float* adst   = (float*)alloc(sizeof(float) * (size_t)NN * 4);
  float* xp3    = (float*)alloc(sizeof(float) * (size_t)NN * 2);
  float* asrc3  = (float*)alloc(sizeof(float) * (size_t)NN);
  float* adst3  = (float*)alloc(sizeof(float) * (size_t)NN);
  int* bucketCnt = (int*)alloc(sizeof(int) * (size_t)NBUCK);
  int* pBase    = (int*)alloc(sizeof(int) * (size_t)(NBUCK + 1));
  int* rBase    = (int*)alloc(sizeof(int) * (size_t)(NBUCK + 1));
  int* bcur     = (int*)alloc(sizeof(int) * (size_t)NBUCK);
  int* row_ofs  = (int*)alloc(sizeof(int) * (size_t)(NN + 1));

  hipMemsetAsync(bucketCnt, 0, NBUCK * sizeof(int), stream);

  compute_M_k<<<1, 64, 0, stream>>>(We1, ae1, We2, ae2, We3, ae3, Mbuf);
  bcount_k<<<256, 256, 0, stream>>>(dstA, bucketCnt);
  bscan_k<<<1, 1024, 0, stream>>>(bucketCnt, pBase, rBase, bcur);
  bscat_k<<<200, 256, 0, stream>>>(dstA, srcA, bcur, pairs);
  cbuild_k<<<NBUCK, 256, 0, stream>>>(pBase, rBase, pairs, ea, Mbuf,
                                      recAE1, recAE2, rec3, recSrc, row_ofs, meanp);
  selfloop_k<<<1, 256, 0, stream>>>(meanp, Mbuf, asl);
  slrec_k<<<(NN + 255) / 256, 256, 0, stream>>>(row_ofs, asl, recAE1, recAE2, rec3, recSrc);

  // ---- layer 1 ----
  gemm128a_k<<<dim3((NN + 63) / 64, 2), 256, 0, stream>>>(x, W1, as1, ad1, xp, asrc, adst, NN);
  agg128_k<<<NN, 128, 0, stream>>>(row_ofs, (const unsigned*)recAE1, recSrc, xp,
                                   asrc, adst, b1, g1, be1, rm1, rv1, hbuf);
  // ---- layer 2 ----
  gemm128a_k<<<dim3((NN + 63) / 64, 2), 256, 0, stream>>>(hbuf, W2, as2, ad2, xp, asrc, adst, NN);
  agg128_k<<<NN, 128, 0, stream>>>(row_ofs, (const unsigned*)recAE2, recSrc, xp,
                                   asrc, adst, b2, g2, be2, rm2, rv2, hbuf);
  // ---- layer 3 ----
  xp3_k<<<(NN + 255) / 256, 256, 0, stream>>>(hbuf, W3, as3, ad3, xp3, asrc3, adst3);
  agg2_k<<<(NN + 3) / 4, 256, 0, stream>>>(row_ofs, rec3, recSrc, xp3, asrc3, adst3,
                                           b3, (float*)d_out);
}